// Round 16
// baseline (173.278 us; speedup 1.0000x reference)
//
#include <hip/hip_runtime.h>
#include <hip/hip_bf16.h>
#include <math.h>

typedef __hip_bfloat16 bf16;
typedef float f32x4 __attribute__((ext_vector_type(4)));
typedef short s16x8 __attribute__((ext_vector_type(8)));

typedef const __attribute__((address_space(1))) void* as1cvp;
typedef __attribute__((address_space(3))) void* as3vp;

__device__ __forceinline__ unsigned short f2bf(float f) {
  unsigned u = __float_as_uint(f);
  u += 0x7FFFu + ((u >> 16) & 1u);   // RNE
  return (unsigned short)(u >> 16);
}
__device__ __forceinline__ float bf2f(unsigned short s) {
  return __uint_as_float(((unsigned)s) << 16);
}

__device__ __forceinline__ void gpu_barrier() {
  asm volatile("" ::: "memory");
  __builtin_amdgcn_s_barrier();
  asm volatile("" ::: "memory");
}

// triangle index decode: xt -> (ti<=tj), tj major (generic, used up to 136)
__device__ __forceinline__ void tri_decode(int xt, int* ti_out, int* tj_out) {
  int tj = (int)((sqrtf(8.0f * (float)xt + 1.0f) - 1.0f) * 0.5f);
  int tri = tj * (tj + 1) / 2;
  if (xt < tri) { --tj; tri = tj * (tj + 1) / 2; }
  else if (xt >= tri + tj + 1) { ++tj; tri = tj * (tj + 1) / 2; }
  *ti_out = xt - tri;
  *tj_out = tj;
}

// ---------- fused: x -> xb + xT (z<4, R13-proven transpose) ; weights (z>=4) --
__global__ __launch_bounds__(256) void cast_fused(const float* __restrict__ x,
                                                  unsigned short* __restrict__ xb,
                                                  unsigned short* __restrict__ xT,
                                                  const float* __restrict__ Wq,
                                                  const float* __restrict__ Wk,
                                                  const float* __restrict__ Wv,
                                                  const float* __restrict__ Wo,
                                                  unsigned short* __restrict__ Wkb,
                                                  unsigned short* __restrict__ Wvb,
                                                  unsigned short* __restrict__ Wqb,
                                                  unsigned short* __restrict__ Wob) {
  const int t = threadIdx.x;
  if (blockIdx.z >= 4) {
    const int zz = blockIdx.z - 4;            // 0..7
    const int seg = zz >> 1;                  // 0..3
    const int blk = (zz & 1) * 256 + blockIdx.y * 32 + blockIdx.x;  // 0..511
    const long flat = ((long)blk * 256 + t) * 8;
    const float* src = (seg == 0) ? Wk : (seg == 1) ? Wv : (seg == 2) ? Wq : Wo;
    f32x4 v0 = *(const f32x4*)&src[flat];
    f32x4 v1 = *(const f32x4*)&src[flat + 4];
    s16x8 o;
    o[0] = (short)f2bf(v0[0]); o[1] = (short)f2bf(v0[1]);
    o[2] = (short)f2bf(v0[2]); o[3] = (short)f2bf(v0[3]);
    o[4] = (short)f2bf(v1[0]); o[5] = (short)f2bf(v1[1]);
    o[6] = (short)f2bf(v1[2]); o[7] = (short)f2bf(v1[3]);
    unsigned short* dst = (seg == 0) ? Wkb : (seg == 1) ? Wvb : (seg == 2) ? Wqb : Wob;
    *(s16x8*)&dst[flat] = o;
    return;
  }
  __shared__ unsigned short tl[128 * 136];
  const int n0 = blockIdx.x * 128, d0 = blockIdx.y * 128, b = blockIdx.z;
  const int rr0 = t >> 4;
  const int u   = t & 15;
  const int dd  = u * 8;
#pragma unroll
  for (int it = 0; it < 8; ++it) {
    const int rr = rr0 + it * 16;
    const float* src = x + ((long)(b * 4096 + n0 + rr)) * 1024 + d0 + dd;
    f32x4 v0 = *(const f32x4*)src;
    f32x4 v1 = *(const f32x4*)(src + 4);
    s16x8 o;
    o[0] = (short)f2bf(v0[0]); o[1] = (short)f2bf(v0[1]);
    o[2] = (short)f2bf(v0[2]); o[3] = (short)f2bf(v0[3]);
    o[4] = (short)f2bf(v1[0]); o[5] = (short)f2bf(v1[1]);
    o[6] = (short)f2bf(v1[2]); o[7] = (short)f2bf(v1[3]);
    *(s16x8*)&xb[((long)(b * 4096 + n0 + rr)) * 1024 + d0 + dd] = o;
    const int phys = u ^ (rr >> 3);
    *(s16x8*)&tl[rr * 136 + phys * 8] = o;
  }
  __syncthreads();

  const int nblk = t & 15, dblk = t >> 4;
  s16x8 row[8];
#pragma unroll
  for (int j = 0; j < 8; ++j) {
    const int n = nblk * 8 + j;
    const int phys = dblk ^ nblk;
    row[j] = *(const s16x8*)&tl[n * 136 + phys * 8];
  }
#pragma unroll
  for (int c = 0; c < 8; ++c) {
    s16x8 col;
#pragma unroll
    for (int j = 0; j < 8; ++j) col[j] = row[j][c];
    *(s16x8*)&xT[((long)(b * 1024 + d0 + dblk * 8 + c)) * 4096 + n0 + nblk * 8] = col;
  }
}

// ---------- red2: out[i] = bf16(P[i] + P[i + 4M elems]), vectorized ----------
__global__ __launch_bounds__(256) void red2(const unsigned short* __restrict__ P,
                                            unsigned short* __restrict__ Out) {
  const long i = ((long)blockIdx.x * 256 + threadIdx.x) * 8;
  s16x8 a = *(const s16x8*)&P[i];
  s16x8 b = *(const s16x8*)&P[i + 4194304];
  s16x8 o;
#pragma unroll
  for (int j = 0; j < 8; ++j)
    o[j] = (short)f2bf(bf2f((unsigned short)a[j]) + bf2f((unsigned short)b[j]));
  *(s16x8*)&Out[i] = o;
}

// ================= 256x256 8-phase bf16 GEMM (R2..R15-proven) ================
// C[m,n] = sum_k A[m,k]*Bt[n,k].  gridmode 0: xt -> (xt/NtN, xt%NtN) tiles.
template<bool OUTF32>
__global__ __launch_bounds__(512, 2) void gemm256(
    const bf16* __restrict__ A, int lda, long aOffY, long aOffZ,
    const bf16* __restrict__ Bt, int ldb, long btOffY, long btOffZ,
    void* __restrict__ Cv, int ldc, long cOffY, long cOffZ,
    const float* __restrict__ bias, int K, int NtN, int gridmode)
{
  __shared__ char lds[131072];

  const int Nx = gridDim.x, Ny = gridDim.y;
  const int lin = blockIdx.x + Nx * (blockIdx.y + Ny * blockIdx.z);
  const int tot = Nx * Ny * gridDim.z;
  const int swz = (lin & 7) * (tot >> 3) + (lin >> 3);
  const int xt = swz % Nx;
  const int r2 = swz / Nx;
  const int y = r2 % Ny, z = r2 / Ny;
  int ti, tj;
  if (gridmode == 1) {
    ti = (int)((0x3221110000ULL >> (4 * xt)) & 15);
    tj = (int)((0x3323213210ULL >> (4 * xt)) & 15);
  } else { ti = xt / NtN; tj = xt % NtN; }
  const int bm = ti * 256, bn = tj * 256;

  A  += (long)z * aOffZ + (long)y * aOffY;
  Bt += (long)z * btOffZ + (long)y * btOffY;

  const int tid  = threadIdx.x;
  const int wid  = tid >> 6;
  const int lane = tid & 63;
  const int wm = wid >> 2;
  const int wn = wid & 3;
  const int frow = lane & 15;
  const int fkb  = (lane >> 4) << 4;
  const unsigned xorv = (unsigned)((lane & 7) << 4);

  const int q0 = (tid * 16) ^ (((tid >> 3) & 7) << 4);
  const int q1 = (8192 + tid * 16) ^ (((tid >> 3) & 7) << 4);
  const int srow0 = q0 >> 7, scol0 = (q0 & 127) >> 1;
  const int srow1 = q1 >> 7, scol1 = (q1 & 127) >> 1;
  const bf16* ag0 = A  + (long)(bm + srow0) * lda + scol0;
  const bf16* ag1 = A  + (long)(bm + srow1) * lda + scol1;
  const bf16* bg0 = Bt + (long)(bn + srow0) * ldb + scol0;
  const bf16* bg1 = Bt + (long)(bn + srow1) * ldb + scol1;

#define STAGE_A(buf, half, kk) do {                                                  \
    __builtin_amdgcn_global_load_lds((as1cvp)(ag0 + (long)(half)*128*lda + (kk)),    \
        (as3vp)(lds + (buf)*32768 + (half)*16384 + wid*1024), 16, 0, 0);             \
    __builtin_amdgcn_global_load_lds((as1cvp)(ag1 + (long)(half)*128*lda + (kk)),    \
        (as3vp)(lds + (buf)*32768 + (half)*16384 + 8192 + wid*1024), 16, 0, 0);      \
  } while (0)
#define STAGE_B(buf, half, kk) do {                                                  \
    __builtin_amdgcn_global_load_lds((as1cvp)(bg0 + (long)(half)*128*ldb + (kk)),    \
        (as3vp)(lds + 65536 + (buf)*32768 + (half)*16384 + wid*1024), 16, 0, 0);     \
    __builtin_amdgcn_global_load_lds((as1cvp)(bg1 + (long)(half)*128*ldb + (kk)),    \
        (as3vp)(lds + 65536 + (buf)*32768 + (half)*16384 + 8192 + wid*1024), 16, 0, 0); \
  } while (0)

  const unsigned paBase = (unsigned)((wm * 64 + frow) * 128 + fkb);
  const unsigned pbBase = (unsigned)(((wn & 1) * 64 + frow) * 128 + fkb);
  const unsigned bHalf  = (unsigned)((wn >> 1) * 16384);

#define RD_A(dst, cur, Mh, mi, kh)                                                   \
  dst = *(const s16x8*)(lds + (cur)*32768 + (Mh)*16384 +                             \
                        ((paBase + (mi)*2048u + (kh)*64u) ^ xorv))
#define RD_B(dst, cur, nj, kh)                                                       \
  dst = *(const s16x8*)(lds + 65536 + (cur)*32768 + bHalf +                          \
                        ((pbBase + (nj)*2048u + (kh)*64u) ^ xorv))

#define MFMA16(base, bb)                                                             \
  __builtin_amdgcn_s_setprio(1);                                                     \
  _Pragma("unroll")                                                                  \
  for (int mi = 0; mi < 4; ++mi)                                                     \
    _Pragma("unroll")                                                                \
    for (int nj = 0; nj < 4; ++nj)                                                   \
      acc[(base) + mi][nj] = __builtin_amdgcn_mfma_f32_16x16x32_bf16(                \
          a[mi], bb[nj], acc[(base) + mi][nj], 0, 0, 0);                             \
  __builtin_amdgcn_s_setprio(0);

#define LGKM0 asm volatile("s_waitcnt lgkmcnt(0)" ::: "memory")
#define VM8   asm volatile("s_waitcnt vmcnt(8)" ::: "memory")

  f32x4 acc[8][4] = {};
  s16x8 a[4], b0[4], b1[4];
  const int NT = K >> 6;

  STAGE_A(0, 0, 0); STAGE_B(0, 0, 0); STAGE_B(0, 1, 0);
  STAGE_A(0, 1, 0);
  {
    const int kk = (NT > 1) ? 64 : 0;
    STAGE_A(1, 0, kk); STAGE_B(1, 0, kk); STAGE_B(1, 1, kk);
  }
  VM8;
  gpu_barrier();

  for (int t = 0; t < NT; ++t) {
    const int cur = t & 1, nxt = cur ^ 1;
    const int k1 = ((t + 1 < NT) ? (t + 1) : 0) * 64;
    const int k2 = ((t + 2 < NT) ? (t + 2) : 0) * 64;

#pragma unroll
    for (int mi = 0; mi < 4; ++mi) RD_A(a[mi], cur, 0, mi, 0);
#pragma unroll
    for (int nj = 0; nj < 4; ++nj) RD_B(b0[nj], cur, nj, 0);
    STAGE_A(nxt, 1, k1);
    gpu_barrier(); LGKM0;
    MFMA16(0, b0)
    gpu_barrier();

#pragma unroll
    for (int mi = 0; mi < 4; ++mi) RD_A(a[mi], cur, 0, mi, 1);
#pragma unroll
    for (int nj = 0; nj < 4; ++nj) RD_B(b1[nj], cur, nj, 1);
    gpu_barrier(); LGKM0;
    MFMA16(0, b1)
    VM8;
    gpu_barrier();

#pragma unroll
    for (int mi = 0; mi < 4; ++mi) RD_A(a[mi], cur, 1, mi, 0);
    STAGE_A(cur, 0, k2); STAGE_B(cur, 0, k2); STAGE_B(cur, 1, k2);
    gpu_barrier(); LGKM0;
    MFMA16(4, b0)
    gpu_barrier();

#pragma unroll
    for (int mi = 0; mi < 4; ++mi) RD_A(a[mi], cur, 1, mi, 1);
    gpu_barrier(); LGKM0;
    MFMA16(4, b1)
    VM8;
    gpu_barrier();
  }

  asm volatile("s_waitcnt vmcnt(0)" ::: "memory");

  const int crow0 = bm + wm * 64 + (lane >> 4) * 4;
  const int ccol0 = bn + wn * 64 + (lane & 15);
  if (OUTF32) {
    float* C = (float*)Cv + (long)z * cOffZ + (long)y * cOffY;
    float bs[4];
#pragma unroll
    for (int j = 0; j < 4; ++j) bs[j] = bias ? bias[ccol0 + j * 16] : 0.0f;
#pragma unroll
    for (int i = 0; i < 8; ++i) {
      const int row = crow0 + (i >> 2) * 128 + (i & 3) * 16;
#pragma unroll
      for (int j = 0; j < 4; ++j) {
        const int col = ccol0 + j * 16;
#pragma unroll
        for (int r = 0; r < 4; ++r)
          C[(long)(row + r) * ldc + col] = acc[i][j][r] + bs[j];
      }
    }
  } else {
    unsigned short* C = (unsigned short*)Cv + (long)z * cOffZ + (long)y * cOffY;
#pragma unroll
    for (int i = 0; i < 8; ++i) {
      const int row = crow0 + (i >> 2) * 128 + (i & 3) * 16;
#pragma unroll
      for (int j = 0; j < 4; ++j) {
        const int col = ccol0 + j * 16;
#pragma unroll
        for (int r = 0; r < 4; ++r)
          C[(long)(row + r) * ldc + col] = f2bf(acc[i][j][r]);
      }
    }
  }
#undef STAGE_A
#undef STAGE_B
#undef RD_A
#undef RD_B
#undef MFMA16
#undef LGKM0
#undef VM8
}

// ================= 128x128 bf16 GEMM, 4 waves, 64KB LDS dbuf 2-phase =========
// Proven R7..R15 schedule.  XOR swizzle both-sides.
// MODE 4: split-K2 bf16 partial: grid (64,8); yy = split*4+batch; Kp=512;
//         A += split*512, Bt = B0 + batch*1M + split*512, C = Cv + yy*1M.
template<int MODE>
__global__ __launch_bounds__(256) void gemm128(
    const bf16* __restrict__ A0, const bf16* __restrict__ B0,
    void* __restrict__ Cv, int Kp)
{
  __shared__ char lds[65536];   // A: [2][16K] ; B at +32768: [2][16K]

  const int Nx = gridDim.x;
  const int lin = blockIdx.x + Nx * blockIdx.y;
  const int tot = Nx * gridDim.y;
  const int swz = (lin & 7) * (tot >> 3) + (lin >> 3);   // tot%8==0
  const int xt = swz % Nx, yy = swz / Nx;

  const int lda = 1024;
  const int ldb = 1024;
  const int bm = (xt >> 3) * 128, bn = (xt & 7) * 128;
  const int batch = yy & 3, split = yy >> 2;
  const bf16* A  = A0 + split * 512;                      // weights, shared
  const bf16* Bt = B0 + (long)batch * 1048576L + split * 512;

  const int tid  = threadIdx.x;
  const int wid  = tid >> 6;
  const int lane = tid & 63;
  const int wr = (wid >> 1) * 64, wc = (wid & 1) * 64;
  const int frow = lane & 15;
  const int fkb  = (lane >> 4) << 4;
  const unsigned xorv = (unsigned)((lane & 7) << 4);

  // staging source: LDS linear p -> global q = p ^ (((p>>7)&7)<<4)
  const int q0 = (tid * 16) ^ (((tid >> 3) & 7) << 4);
  const int srow0 = q0 >> 7, scol0 = (q0 & 127) >> 1;
  const bf16* ag = A  + (long)(bm + srow0) * lda + scol0;
  const bf16* bg = Bt + (long)(bn + srow0) * ldb + scol0;

#define STG128(buf, kk) do {                                                         \
    _Pragma("unroll")                                                                \
    for (int i = 0; i < 4; ++i) {                                                    \
      __builtin_amdgcn_global_load_lds((as1cvp)(ag + (long)i * 32 * lda + (kk)),     \
          (as3vp)(lds + (buf) * 16384 + i * 4096 + tid * 16), 16, 0, 0);             \
      __builtin_amdgcn_global_load_lds((as1cvp)(bg + (long)i * 32 * ldb + (kk)),     \
          (as3vp)(lds + 32768 + (buf) * 16384 + i * 4096 + tid * 16), 16, 0, 0);     \
    }                                                                                \
  } while (0)

  const unsigned paB = (unsigned)((wr + frow) * 128 + fkb);
  const unsigned pbB = (unsigned)((wc + frow) * 128 + fkb);

  f32x4 acc[4][4] = {};
  const int NT = Kp >> 6;

  // prologue: tile 0 fully landed before any read
  STG128(0, 0);
  asm volatile("s_waitcnt vmcnt(0)" ::: "memory");
  gpu_barrier();

  for (int t = 0; t < NT; ++t) {
    const int cur = t & 1;
    if (t + 1 < NT) STG128(cur ^ 1, (t + 1) * 64);   // issue next (not waited)
    s16x8 a[4][2], b[4][2];
#pragma unroll
    for (int mi = 0; mi < 4; ++mi)
#pragma unroll
      for (int kh = 0; kh < 2; ++kh)
        a[mi][kh] = *(const s16x8*)(lds + cur * 16384 +
                                    ((paB + mi * 2048u + kh * 64u) ^ xorv));
#pragma unroll
    for (int nj = 0; nj < 4; ++nj)
#pragma unroll
      for (int kh = 0; kh < 2; ++kh)
        b[nj][kh] = *(const s16x8*)(lds + 32768 + cur * 16384 +
                                    ((pbB + nj * 2048u + kh * 64u) ^ xorv));
    asm volatile("s_waitcnt lgkmcnt(0)" ::: "memory");
#pragma unroll
    for (int mi = 0; mi < 4; ++mi)
#pragma unroll
      for (int nj = 0; nj < 4; ++nj) {
        acc[mi][nj] = __builtin_amdgcn_mfma_f32_16x16x32_bf16(a[mi][0], b[nj][0], acc[mi][nj], 0, 0, 0);
        acc[mi][nj] = __builtin_amdgcn_mfma_f32_16x16x32_bf16(a[mi][1], b[nj][1], acc[mi][nj], 0, 0, 0);
      }
    // full drain: next-tile loads landed; all waves past reads of buf cur
    asm volatile("s_waitcnt vmcnt(0)" ::: "memory");
    gpu_barrier();
  }

  const int r0 = wr + (lane >> 4) * 4;
  const int c0t = wc + (lane & 15);
  unsigned short* C = (unsigned short*)Cv + (long)yy * 1048576;
#pragma unroll
  for (int mi = 0; mi < 4; ++mi)
#pragma unroll
    for (int nj = 0; nj < 4; ++nj)
#pragma unroll
      for (int r = 0; r < 4; ++r)
        C[(long)(bm + r0 + mi * 16 + r) * 1024 + bn + c0t + nj * 16] =
            f2bf(acc[mi][nj][r]);
#undef STG128
}

// ================= 64x64 bf16 GEMM, 4 waves, dbuf LDS, swizzled (R7) =========
// dmode 0: rect; dmode 1: diag (xt,xt); dmode 2: triangle.
// OUTMODE 1: f32 compact per-tile.  OUTMODE 3: bf16 [1024][1024] + mirror (Gram).
template<int OUTMODE>
__global__ __launch_bounds__(256) void gemm64(
    const bf16* __restrict__ A, int lda, long aOffZ,
    const bf16* __restrict__ Bt, int ldb, long btOffZ,
    void* __restrict__ Cv, int ldc, long cOffZ, int loOff,
    int K, int NtN, int dmode, int ksplit)
{
  __shared__ char lds[32768];   // A: [2][8K] ; B at +16384, same

  const int Nx = gridDim.x;
  const int lin = blockIdx.x + Nx * blockIdx.y;
  const int tot = Nx * gridDim.y;
  const int swz = (lin & 7) * (tot >> 3) + (lin >> 3);  // tot%8==0 at all calls
  const int xt = swz % Nx, y = swz / Nx;
  const int zb = y / ksplit, zs = y % ksplit;
  int ti, tj;
  if (dmode == 2)      { tri_decode(xt, &ti, &tj); }
  else if (dmode == 1) { ti = xt; tj = xt; }
  else                 { ti = xt / NtN; tj = xt % NtN; }
  const int bm = ti * 64, bn = tj * 64;

  A  += (long)zb * aOffZ + (long)zs * K;
  Bt += (long)zb * btOffZ + (long)zs * K;

  const int tid  = threadIdx.x;
  const int wid  = tid >> 6;
  const int lane = tid & 63;
  const int wr = (wid >> 1) * 32, wc = (wid & 1) * 32;
  const int frow = lane & 15;
  const int fkb  = (lane >> 4) << 4;
  const unsigned xorv = (unsigned)((lane & 7) << 4);

  // staging source: LDS linear p -> global q = p ^ (((p>>7)&7)<<4)
  const int q0 = (tid * 16) ^ (((tid >> 3) & 7) << 4);
  const int q1 = (4096 + tid * 16) ^ (((tid >> 3) & 7) << 4);
  const int srow0 = q0 >> 7, scol0 = (q0 & 127) >> 1;
  const int srow1 = q1 >> 7, scol1 = (q1 & 127) >> 1;
  const bf16* ag0 = A  + (long)(bm + srow0) * lda + scol0;
  const bf16* ag1 = A  + (long)(bm + srow1) * lda + scol1;
  const bf16* bg0 = Bt + (long)(bn + srow0) * ldb + scol0;
  const bf16* bg1 = Bt + (long)(bn + srow1) * ldb + scol1;

#define STAGE64(buf, kk) do {                                                        \
    __builtin_amdgcn_global_load_lds((as1cvp)(ag0 + (kk)),                           \
        (as3vp)(lds + (buf)*8192 + wid*1024), 16, 0, 0);                             \
    __builtin_amdgcn_global_load_lds((as1cvp)(ag1 + (kk)),                           \
        (as3vp)(lds + (buf)*8192 + 4096 + wid*1024), 16, 0, 0);                      \
    __builtin_amdgcn_global_load_lds((as1cvp)(bg0 + (kk)),                           \
        (as3vp)(lds + 16384 + (buf)*8192 + wid*1024), 16, 0, 0);                     \
    __builtin_amdgcn_global_load_lds((as1cvp)(bg1 + (kk)),                           \
        (as3vp)(lds + 16384 + (buf)*8192 + 4096 + wid*1024), 16, 0, 0);              \
  } while (0)

  const unsigned paB = (unsigned)((wr + frow) * 128 + fkb);
  const unsigned pbB = (unsigned)((wc + frow) * 128 + fkb);

  f32x4 acc[2][2] = {};
  const int NT = K >> 6;

  // prologue: tile 0 fully landed before any read
  STAGE64(0, 0);
  asm volatile("s_waitcnt vmcnt(0)" ::: "memory");
  gpu_barrier();

  for (int t = 0; t < NT; ++t) {
    const int cur = t & 1;
    if (t + 1 < NT) STAGE64(cur ^ 1, (t + 1) * 64);   // issue next (not waited)
    s16x8 a[2][2], b[2][2];
#pragma unroll
    for (int mi = 0; mi < 2; ++mi)
#pragma unroll
      for (int kh = 0; kh < 2; ++kh)
        a[mi][kh] = *(const s16x8*)(lds + cur * 8192 +
                                    ((paB + mi * 2048u + kh * 64u) ^ xorv));
#pragma unroll
    for (int nj = 0; nj < 2; ++nj)
#pragma unroll
      for (int kh = 0; kh < 2; ++kh)
        b[nj][kh] = *(const s16x8*)(lds + 16384 + cur * 8192 +
                                    ((pbB + nj * 2048u + kh * 64u) ^ xorv));
    asm volatile("s_waitcnt lgkmcnt(0)" ::: "memory");
#pragma unroll
    for (int mi = 0; mi < 2; ++mi)
#pragma unroll
      for (int nj = 0; nj < 2; ++nj) {
        acc[mi][nj] = __builtin_amdgcn_mfma_f32_16x16x32_bf16(a[mi][0], b[nj][0], acc[mi][nj], 0, 0, 0);
        acc[mi][nj] = __builtin_amdgcn_mfma_f32_16x16x32_bf16(a[mi][1], b[nj][1], acc[mi][nj], 0, 0, 0);
      }
    // full drain: next-tile loads landed; all waves past reads of buf cur
    asm volatile("s_waitcnt vmcnt(0)" ::: "memory");
    gpu_barrier();
  }

  const int r0 = wr + (lane >> 4) * 4;
  const int c0 = wc + (lane & 15);
  if (OUTMODE == 1) {
    float* C = (float*)Cv + (long)y * cOffZ + (long)xt * 4096;
#pragma unroll
    for (int mi = 0; mi < 2; ++mi)
#pragma unroll
      for (int nj = 0; nj < 2; ++nj)
#pragma unroll
        for (int r = 0; r < 4; ++r)
          C[(r0 + mi * 16 + r) * 64 + c0 + nj * 16] = acc[mi][nj][r];
  } else if (OUTMODE == 3) {
    // Gram: bf16 G[1024][1024] per batch + symmetric mirror
    unsigned short* C = (unsigned short*)Cv + (long)y * cOffZ;
#pragma unroll
    for (int mi = 0; mi < 2; ++mi)
#pragma unroll
      for (int nj = 0; nj < 2; ++nj)
#pragma unroll
        for (int r = 0; r < 4; ++r) {
          const unsigned short h = f2bf(acc[mi][nj][r]);
          const int R = bm + r0 + mi * 16 + r;
          const int Cc = bn + c0 + nj * 16;
          C[(long)R * 1024 + Cc] = h;
          if (ti != tj) C[(long)Cc * 1024 + R] = h;
        }
  } else {
    unsigned short* C = (unsigned short*)Cv + (long)y * cOffZ;
#pragma unroll
    for (int mi = 0; mi < 2; ++mi)
#pragma unroll
      for (int nj = 0; nj < 2; ++nj)
#pragma unroll
        for (int r = 0; r < 4; ++r) {
          const float v = acc[mi][nj][r];
          const unsigned short h = f2bf(v);
          const long idx = (long)(bm + r0 + mi * 16 + r) * ldc + bn + c0 + nj * 16;
          C[idx] = h;
          if (OUTMODE == 2) C[idx + loOff] = f2bf(v - bf2f(h));
        }
  }
#undef STAGE64
}

// ---------- Yt[b][c][h*64+e] = 0.125 * sum_d (sum_s Up) * Wq[h*64+d][c] ------
__global__ __launch_bounds__(256) void yt_kernel(const float* __restrict__ Up,
                                                 const unsigned short* __restrict__ Wqb,
                                                 unsigned short* __restrict__ Yt) {
  __shared__ float Ul[64 * 64];
  __shared__ float Wql[64 * 68];
  const int cblk = blockIdx.x, h = blockIdx.y, z = blockIdx.z;
  const int t = threadIdx.x;

  {
    const int d = t >> 2, e0 = (t & 3) * 16;
#pragma unroll
    for (int q = 0; q < 4; ++q) {
      f32x4 s = {};
#pragma unroll
      for (int sp = 0; sp < 4; ++sp) {
        f32x4 v = *(const f32x4*)&Up[((long)(z * 4 + sp) * 16 + h) * 4096 + d * 64 + e0 + q * 4];
#pragma unroll
        for (int j = 0; j < 4; ++j) s[j] += v[j];
      }
      *(f32x4*)&Ul[d * 64 + e0 + q * 4] = s;
    }
    const unsigned short* wp = Wqb + (long)(h * 64 + d) * 1024 + cblk * 64 + e0;
#pragma unroll
    for (int q = 0; q < 2; ++q) {
      s16x8 w = *(const s16x8*)&wp[q * 8];
#pragma unroll
      for (int j = 0; j < 8; ++j) Wql[d * 68 + e0 + q * 8 + j] = bf2f((unsigned short)w[j]);
    }
  }
  __syncthreads();

  const int jc = t >> 2, e0 = (t & 3) * 16;
  f32x4 acc[4] = {};
  for (int d = 0; d < 64; ++d) {
    const float w = Wql[d * 68 + jc];
    const float* ur = &Ul[d * 64 + e0];
#pragma unroll
    for (int q = 0; q < 4; ++q) {
      f32x4 u4 = *(const f32x4*)&ur[q * 4];
#pragma unroll
      for (int j = 0; j < 4; ++j) acc[q][j] += w * u4[j];
    }
  }
  unsigned short* yp = Yt + (long)z * 1048576 + (long)(cblk * 64 + jc) * 1024 + h * 64 + e0;
#pragma unroll
  for (int q = 0; q < 4; ++q)
#pragma unroll
    for (int j = 0; j < 4; ++j) yp[q * 4 + j] = f2bf(acc[q][j] * 0.125f);
}

extern "C" void kernel_launch(void* const* d_in, const int* in_sizes, int n_in,
                              void* d_out, int out_size, void* d_ws, size_t ws_size,
                              hipStream_t stream) {
  const float* x  = (const float*)d_in[0];
  const float* Wq = (const float*)d_in[1];
  const float* Wk = (const float*)d_in[2];
  const float* Wv = (const float*)d_in[3];
  const float* Wo = (const float*)d_in[4];
  const float* bo = (const float*)d_in[5];
  float* out = (float*)d_out;

  char* ws = (char*)d_ws;
  // layout (bytes): [0,32M) xb | [32M,64M) xT | [64M,76M) weights |
  //   Gb @79691776 (8.4M) | T @88080384 (8.4M) | Pp @96468992 (16.8M) |
  //   Yt @113246208 (8.4M) | R @121634816 (8.4M) | Up @130023424 (4.2M)
  unsigned short* xb  = (unsigned short*)(ws);
  unsigned short* xT  = (unsigned short*)(ws + 33554432);
  unsigned short* Wkb = (unsigned short*)(ws + 67108864);
  unsigned short* Wvb = (unsigned short*)(ws + 71303168);
  unsigned short* Wqb = (unsigned short*)(ws + 75497472);
  unsigned short* Wob = (unsigned short*)(ws + 77594624);
  unsigned short* Gb  = (unsigned short*)(ws + 79691776);
  unsigned short* T   = (unsigned short*)(ws + 88080384);
  unsigned short* Pp  = (unsigned short*)(ws + 96468992);
  unsigned short* Yt  = (unsigned short*)(ws + 113246208);
  unsigned short* R   = (unsigned short*)(ws + 121634816);
  float*          Up  = (float*)         (ws + 130023424);

  // 1) fused casts: x -> xb + xT ; weights -> Wkb/Wvb/Wqb/Wob
  cast_fused<<<dim3(32, 8, 12), 256, 0, stream>>>(
      x, xb, xT, Wq, Wk, Wv, Wo, Wkb, Wvb, Wqb, Wob);

  // 2) G = xT . xT^T direct: 64^2 triangle (136) x 4 batches, K=4096, + mirror
  gemm64<3><<<dim3(136, 4), 256, 0, stream>>>(
      (const bf16*)xT, 4096, 4194304L, (const bf16*)xT, 4096, 4194304L,
      (void*)Gb, 1024, 1048576L, 0, 4096, 1, 2, 1);

  // 3) T partials = Wk . G, split-K2 (512 wgs), bf16; then reduce
  gemm128<4><<<dim3(64, 8), 256, 0, stream>>>(
      (const bf16*)Wkb, (const bf16*)Gb, (void*)Pp, 512);
  red2<<<2048, 256, 0, stream>>>(Pp, T);

  // 4) Up = T . Wv^T diag 64-tiles, K-split 4 (y = b*4+s, K=256), fp32 compact
  gemm64<1><<<dim3(16, 16), 256, 0, stream>>>(
      (const bf16*)T, 1024, 1048576L, (const bf16*)Wvb, 1024, 0L,
      (void*)Up, 64, 65536L, 0, 256, 1, 1, 4);

  // 5) Yt from Up (sums 4 splits) and Wq (applies 0.125 scale)
  yt_kernel<<<dim3(16, 16, 4), 256, 0, stream>>>(Up, Wqb, Yt);

  // 6) R partials = Wo . Y, split-K2 (512 wgs), bf16; then reduce
  gemm128<4><<<dim3(64, 8), 256, 0, stream>>>(
      (const bf16*)Wob, (const bf16*)Yt, (void*)Pp, 512);
  red2<<<2048, 256, 0, stream>>>(Pp, R);

  // 7) out = xb . R_b^T + bo  (8-phase gemm256, proven 45.4us)
  gemm256<true><<<dim3(64, 1, 4), 512, 0, stream>>>(
      (const bf16*)xb, 1024, 0L, 4194304L,
      (const bf16*)R, 1024, 0L, 1048576L,
      (void*)out, 1024, 0L, 4194304L,
      bo, 1024, 4, 0);
}

// Round 17
// 163.556 us; speedup vs baseline: 1.0594x; 1.0594x over previous
//
#include <hip/hip_runtime.h>
#include <hip/hip_bf16.h>
#include <math.h>

typedef __hip_bfloat16 bf16;
typedef float f32x4 __attribute__((ext_vector_type(4)));
typedef short s16x8 __attribute__((ext_vector_type(8)));

typedef const __attribute__((address_space(1))) void* as1cvp;
typedef __attribute__((address_space(3))) void* as3vp;

__device__ __forceinline__ unsigned short f2bf(float f) {
  unsigned u = __float_as_uint(f);
  u += 0x7FFFu + ((u >> 16) & 1u);   // RNE
  return (unsigned short)(u >> 16);
}
__device__ __forceinline__ float bf2f(unsigned short s) {
  return __uint_as_float(((unsigned)s) << 16);
}

__device__ __forceinline__ void gpu_barrier() {
  asm volatile("" ::: "memory");
  __builtin_amdgcn_s_barrier();
  asm volatile("" ::: "memory");
}

// triangle index decode: xt -> (ti<=tj), tj major (generic, used up to 136)
__device__ __forceinline__ void tri_decode(int xt, int* ti_out, int* tj_out) {
  int tj = (int)((sqrtf(8.0f * (float)xt + 1.0f) - 1.0f) * 0.5f);
  int tri = tj * (tj + 1) / 2;
  if (xt < tri) { --tj; tri = tj * (tj + 1) / 2; }
  else if (xt >= tri + tj + 1) { ++tj; tri = tj * (tj + 1) / 2; }
  *ti_out = xt - tri;
  *tj_out = tj;
}

// ---------- fused: x -> xb + xT (z<4, R13-proven transpose) ; weights (z>=4) --
__global__ __launch_bounds__(256) void cast_fused(const float* __restrict__ x,
                                                  unsigned short* __restrict__ xb,
                                                  unsigned short* __restrict__ xT,
                                                  const float* __restrict__ Wq,
                                                  const float* __restrict__ Wk,
                                                  const float* __restrict__ Wv,
                                                  const float* __restrict__ Wo,
                                                  unsigned short* __restrict__ Wkb,
                                                  unsigned short* __restrict__ Wvb,
                                                  unsigned short* __restrict__ Wqb,
                                                  unsigned short* __restrict__ Wob) {
  const int t = threadIdx.x;
  if (blockIdx.z >= 4) {
    const int zz = blockIdx.z - 4;            // 0..7
    const int seg = zz >> 1;                  // 0..3
    const int blk = (zz & 1) * 256 + blockIdx.y * 32 + blockIdx.x;  // 0..511
    const long flat = ((long)blk * 256 + t) * 8;
    const float* src = (seg == 0) ? Wk : (seg == 1) ? Wv : (seg == 2) ? Wq : Wo;
    f32x4 v0 = *(const f32x4*)&src[flat];
    f32x4 v1 = *(const f32x4*)&src[flat + 4];
    s16x8 o;
    o[0] = (short)f2bf(v0[0]); o[1] = (short)f2bf(v0[1]);
    o[2] = (short)f2bf(v0[2]); o[3] = (short)f2bf(v0[3]);
    o[4] = (short)f2bf(v1[0]); o[5] = (short)f2bf(v1[1]);
    o[6] = (short)f2bf(v1[2]); o[7] = (short)f2bf(v1[3]);
    unsigned short* dst = (seg == 0) ? Wkb : (seg == 1) ? Wvb : (seg == 2) ? Wqb : Wob;
    *(s16x8*)&dst[flat] = o;
    return;
  }
  __shared__ unsigned short tl[128 * 136];
  const int n0 = blockIdx.x * 128, d0 = blockIdx.y * 128, b = blockIdx.z;
  const int rr0 = t >> 4;
  const int u   = t & 15;
  const int dd  = u * 8;
#pragma unroll
  for (int it = 0; it < 8; ++it) {
    const int rr = rr0 + it * 16;
    const float* src = x + ((long)(b * 4096 + n0 + rr)) * 1024 + d0 + dd;
    f32x4 v0 = *(const f32x4*)src;
    f32x4 v1 = *(const f32x4*)(src + 4);
    s16x8 o;
    o[0] = (short)f2bf(v0[0]); o[1] = (short)f2bf(v0[1]);
    o[2] = (short)f2bf(v0[2]); o[3] = (short)f2bf(v0[3]);
    o[4] = (short)f2bf(v1[0]); o[5] = (short)f2bf(v1[1]);
    o[6] = (short)f2bf(v1[2]); o[7] = (short)f2bf(v1[3]);
    *(s16x8*)&xb[((long)(b * 4096 + n0 + rr)) * 1024 + d0 + dd] = o;
    const int phys = u ^ (rr >> 3);
    *(s16x8*)&tl[rr * 136 + phys * 8] = o;
  }
  __syncthreads();

  const int nblk = t & 15, dblk = t >> 4;
  s16x8 row[8];
#pragma unroll
  for (int j = 0; j < 8; ++j) {
    const int n = nblk * 8 + j;
    const int phys = dblk ^ nblk;
    row[j] = *(const s16x8*)&tl[n * 136 + phys * 8];
  }
#pragma unroll
  for (int c = 0; c < 8; ++c) {
    s16x8 col;
#pragma unroll
    for (int j = 0; j < 8; ++j) col[j] = row[j][c];
    *(s16x8*)&xT[((long)(b * 1024 + d0 + dblk * 8 + c)) * 4096 + n0 + nblk * 8] = col;
  }
}

// ================= 256x256 8-phase bf16 GEMM (R2..R15-proven) ================
// C[m,n] = sum_k A[m,k]*Bt[n,k].  gridmode 0: xt -> (xt/NtN, xt%NtN) tiles.
template<bool OUTF32>
__global__ __launch_bounds__(512, 2) void gemm256(
    const bf16* __restrict__ A, int lda, long aOffY, long aOffZ,
    const bf16* __restrict__ Bt, int ldb, long btOffY, long btOffZ,
    void* __restrict__ Cv, int ldc, long cOffY, long cOffZ,
    const float* __restrict__ bias, int K, int NtN, int gridmode)
{
  __shared__ char lds[131072];

  const int Nx = gridDim.x, Ny = gridDim.y;
  const int lin = blockIdx.x + Nx * (blockIdx.y + Ny * blockIdx.z);
  const int tot = Nx * Ny * gridDim.z;
  const int swz = (lin & 7) * (tot >> 3) + (lin >> 3);
  const int xt = swz % Nx;
  const int r2 = swz / Nx;
  const int y = r2 % Ny, z = r2 / Ny;
  int ti, tj;
  if (gridmode == 1) {
    ti = (int)((0x3221110000ULL >> (4 * xt)) & 15);
    tj = (int)((0x3323213210ULL >> (4 * xt)) & 15);
  } else { ti = xt / NtN; tj = xt % NtN; }
  const int bm = ti * 256, bn = tj * 256;

  A  += (long)z * aOffZ + (long)y * aOffY;
  Bt += (long)z * btOffZ + (long)y * btOffY;

  const int tid  = threadIdx.x;
  const int wid  = tid >> 6;
  const int lane = tid & 63;
  const int wm = wid >> 2;
  const int wn = wid & 3;
  const int frow = lane & 15;
  const int fkb  = (lane >> 4) << 4;
  const unsigned xorv = (unsigned)((lane & 7) << 4);

  const int q0 = (tid * 16) ^ (((tid >> 3) & 7) << 4);
  const int q1 = (8192 + tid * 16) ^ (((tid >> 3) & 7) << 4);
  const int srow0 = q0 >> 7, scol0 = (q0 & 127) >> 1;
  const int srow1 = q1 >> 7, scol1 = (q1 & 127) >> 1;
  const bf16* ag0 = A  + (long)(bm + srow0) * lda + scol0;
  const bf16* ag1 = A  + (long)(bm + srow1) * lda + scol1;
  const bf16* bg0 = Bt + (long)(bn + srow0) * ldb + scol0;
  const bf16* bg1 = Bt + (long)(bn + srow1) * ldb + scol1;

#define STAGE_A(buf, half, kk) do {                                                  \
    __builtin_amdgcn_global_load_lds((as1cvp)(ag0 + (long)(half)*128*lda + (kk)),    \
        (as3vp)(lds + (buf)*32768 + (half)*16384 + wid*1024), 16, 0, 0);             \
    __builtin_amdgcn_global_load_lds((as1cvp)(ag1 + (long)(half)*128*lda + (kk)),    \
        (as3vp)(lds + (buf)*32768 + (half)*16384 + 8192 + wid*1024), 16, 0, 0);      \
  } while (0)
#define STAGE_B(buf, half, kk) do {                                                  \
    __builtin_amdgcn_global_load_lds((as1cvp)(bg0 + (long)(half)*128*ldb + (kk)),    \
        (as3vp)(lds + 65536 + (buf)*32768 + (half)*16384 + wid*1024), 16, 0, 0);     \
    __builtin_amdgcn_global_load_lds((as1cvp)(bg1 + (long)(half)*128*ldb + (kk)),    \
        (as3vp)(lds + 65536 + (buf)*32768 + (half)*16384 + 8192 + wid*1024), 16, 0, 0); \
  } while (0)

  const unsigned paBase = (unsigned)((wm * 64 + frow) * 128 + fkb);
  const unsigned pbBase = (unsigned)(((wn & 1) * 64 + frow) * 128 + fkb);
  const unsigned bHalf  = (unsigned)((wn >> 1) * 16384);

#define RD_A(dst, cur, Mh, mi, kh)                                                   \
  dst = *(const s16x8*)(lds + (cur)*32768 + (Mh)*16384 +                             \
                        ((paBase + (mi)*2048u + (kh)*64u) ^ xorv))
#define RD_B(dst, cur, nj, kh)                                                       \
  dst = *(const s16x8*)(lds + 65536 + (cur)*32768 + bHalf +                          \
                        ((pbBase + (nj)*2048u + (kh)*64u) ^ xorv))

#define MFMA16(base, bb)                                                             \
  __builtin_amdgcn_s_setprio(1);                                                     \
  _Pragma("unroll")                                                                  \
  for (int mi = 0; mi < 4; ++mi)                                                     \
    _Pragma("unroll")                                                                \
    for (int nj = 0; nj < 4; ++nj)                                                   \
      acc[(base) + mi][nj] = __builtin_amdgcn_mfma_f32_16x16x32_bf16(                \
          a[mi], bb[nj], acc[(base) + mi][nj], 0, 0, 0);                             \
  __builtin_amdgcn_s_setprio(0);

#define LGKM0 asm volatile("s_waitcnt lgkmcnt(0)" ::: "memory")
#define VM8   asm volatile("s_waitcnt vmcnt(8)" ::: "memory")

  f32x4 acc[8][4] = {};
  s16x8 a[4], b0[4], b1[4];
  const int NT = K >> 6;

  STAGE_A(0, 0, 0); STAGE_B(0, 0, 0); STAGE_B(0, 1, 0);
  STAGE_A(0, 1, 0);
  {
    const int kk = (NT > 1) ? 64 : 0;
    STAGE_A(1, 0, kk); STAGE_B(1, 0, kk); STAGE_B(1, 1, kk);
  }
  VM8;
  gpu_barrier();

  for (int t = 0; t < NT; ++t) {
    const int cur = t & 1, nxt = cur ^ 1;
    const int k1 = ((t + 1 < NT) ? (t + 1) : 0) * 64;
    const int k2 = ((t + 2 < NT) ? (t + 2) : 0) * 64;

#pragma unroll
    for (int mi = 0; mi < 4; ++mi) RD_A(a[mi], cur, 0, mi, 0);
#pragma unroll
    for (int nj = 0; nj < 4; ++nj) RD_B(b0[nj], cur, nj, 0);
    STAGE_A(nxt, 1, k1);
    gpu_barrier(); LGKM0;
    MFMA16(0, b0)
    gpu_barrier();

#pragma unroll
    for (int mi = 0; mi < 4; ++mi) RD_A(a[mi], cur, 0, mi, 1);
#pragma unroll
    for (int nj = 0; nj < 4; ++nj) RD_B(b1[nj], cur, nj, 1);
    gpu_barrier(); LGKM0;
    MFMA16(0, b1)
    VM8;
    gpu_barrier();

#pragma unroll
    for (int mi = 0; mi < 4; ++mi) RD_A(a[mi], cur, 1, mi, 0);
    STAGE_A(cur, 0, k2); STAGE_B(cur, 0, k2); STAGE_B(cur, 1, k2);
    gpu_barrier(); LGKM0;
    MFMA16(4, b0)
    gpu_barrier();

#pragma unroll
    for (int mi = 0; mi < 4; ++mi) RD_A(a[mi], cur, 1, mi, 1);
    gpu_barrier(); LGKM0;
    MFMA16(4, b1)
    VM8;
    gpu_barrier();
  }

  asm volatile("s_waitcnt vmcnt(0)" ::: "memory");

  const int crow0 = bm + wm * 64 + (lane >> 4) * 4;
  const int ccol0 = bn + wn * 64 + (lane & 15);
  if (OUTF32) {
    float* C = (float*)Cv + (long)z * cOffZ + (long)y * cOffY;
    float bs[4];
#pragma unroll
    for (int j = 0; j < 4; ++j) bs[j] = bias ? bias[ccol0 + j * 16] : 0.0f;
#pragma unroll
    for (int i = 0; i < 8; ++i) {
      const int row = crow0 + (i >> 2) * 128 + (i & 3) * 16;
#pragma unroll
      for (int j = 0; j < 4; ++j) {
        const int col = ccol0 + j * 16;
#pragma unroll
        for (int r = 0; r < 4; ++r)
          C[(long)(row + r) * ldc + col] = acc[i][j][r] + bs[j];
      }
    }
  } else {
    unsigned short* C = (unsigned short*)Cv + (long)z * cOffZ + (long)y * cOffY;
#pragma unroll
    for (int i = 0; i < 8; ++i) {
      const int row = crow0 + (i >> 2) * 128 + (i & 3) * 16;
#pragma unroll
      for (int j = 0; j < 4; ++j) {
        const int col = ccol0 + j * 16;
#pragma unroll
        for (int r = 0; r < 4; ++r)
          C[(long)(row + r) * ldc + col] = f2bf(acc[i][j][r]);
      }
    }
  }
#undef STAGE_A
#undef STAGE_B
#undef RD_A
#undef RD_B
#undef MFMA16
#undef LGKM0
#undef VM8
}

// ================= 128x128 bf16 GEMM, 4 waves, 64KB LDS dbuf 2-phase =========
// Proven R7..R15 schedule.  XOR swizzle both-sides.
// MODE 3: plain bf16 out, batch-strided B and C (lda=1024, K=1024, grid (64,4))
template<int MODE>
__global__ __launch_bounds__(256) void gemm128(
    const bf16* __restrict__ A0, const bf16* __restrict__ B0,
    void* __restrict__ Cv, const float* __restrict__ bias)
{
  __shared__ char lds[65536];   // A: [2][16K] ; B at +32768: [2][16K]

  const int Nx = gridDim.x;
  const int lin = blockIdx.x + Nx * blockIdx.y;
  const int tot = Nx * gridDim.y;
  const int swz = (lin & 7) * (tot >> 3) + (lin >> 3);   // tot%8==0
  const int xt = swz % Nx, yy = swz / Nx;

  const int lda = 1024;
  const int ldb = 1024;
  const int K   = 1024;
  const int bm = (xt >> 3) * 128, bn = (xt & 7) * 128;
  const bf16* A  = A0;                                    // weights, shared
  const bf16* Bt = B0 + (long)yy * 1048576L;

  const int tid  = threadIdx.x;
  const int wid  = tid >> 6;
  const int lane = tid & 63;
  const int wr = (wid >> 1) * 64, wc = (wid & 1) * 64;
  const int frow = lane & 15;
  const int fkb  = (lane >> 4) << 4;
  const unsigned xorv = (unsigned)((lane & 7) << 4);

  // staging source: LDS linear p -> global q = p ^ (((p>>7)&7)<<4)
  const int q0 = (tid * 16) ^ (((tid >> 3) & 7) << 4);
  const int srow0 = q0 >> 7, scol0 = (q0 & 127) >> 1;
  const bf16* ag = A  + (long)(bm + srow0) * lda + scol0;
  const bf16* bg = Bt + (long)(bn + srow0) * ldb + scol0;

#define STG128(buf, kk) do {                                                         \
    _Pragma("unroll")                                                                \
    for (int i = 0; i < 4; ++i) {                                                    \
      __builtin_amdgcn_global_load_lds((as1cvp)(ag + (long)i * 32 * lda + (kk)),     \
          (as3vp)(lds + (buf) * 16384 + i * 4096 + tid * 16), 16, 0, 0);             \
      __builtin_amdgcn_global_load_lds((as1cvp)(bg + (long)i * 32 * ldb + (kk)),     \
          (as3vp)(lds + 32768 + (buf) * 16384 + i * 4096 + tid * 16), 16, 0, 0);     \
    }                                                                                \
  } while (0)

  const unsigned paB = (unsigned)((wr + frow) * 128 + fkb);
  const unsigned pbB = (unsigned)((wc + frow) * 128 + fkb);

  f32x4 acc[4][4] = {};
  const int NT = K >> 6;

  // prologue: tile 0 fully landed before any read
  STG128(0, 0);
  asm volatile("s_waitcnt vmcnt(0)" ::: "memory");
  gpu_barrier();

  for (int t = 0; t < NT; ++t) {
    const int cur = t & 1;
    if (t + 1 < NT) STG128(cur ^ 1, (t + 1) * 64);   // issue next (not waited)
    s16x8 a[4][2], b[4][2];
#pragma unroll
    for (int mi = 0; mi < 4; ++mi)
#pragma unroll
      for (int kh = 0; kh < 2; ++kh)
        a[mi][kh] = *(const s16x8*)(lds + cur * 16384 +
                                    ((paB + mi * 2048u + kh * 64u) ^ xorv));
#pragma unroll
    for (int nj = 0; nj < 4; ++nj)
#pragma unroll
      for (int kh = 0; kh < 2; ++kh)
        b[nj][kh] = *(const s16x8*)(lds + 32768 + cur * 16384 +
                                    ((pbB + nj * 2048u + kh * 64u) ^ xorv));
    asm volatile("s_waitcnt lgkmcnt(0)" ::: "memory");
#pragma unroll
    for (int mi = 0; mi < 4; ++mi)
#pragma unroll
      for (int nj = 0; nj < 4; ++nj) {
        acc[mi][nj] = __builtin_amdgcn_mfma_f32_16x16x32_bf16(a[mi][0], b[nj][0], acc[mi][nj], 0, 0, 0);
        acc[mi][nj] = __builtin_amdgcn_mfma_f32_16x16x32_bf16(a[mi][1], b[nj][1], acc[mi][nj], 0, 0, 0);
      }
    // full drain: next-tile loads landed; all waves past reads of buf cur
    asm volatile("s_waitcnt vmcnt(0)" ::: "memory");
    gpu_barrier();
  }

  const int r0 = wr + (lane >> 4) * 4;
  const int c0t = wc + (lane & 15);
  unsigned short* C = (unsigned short*)Cv + (long)yy * 1048576;
#pragma unroll
  for (int mi = 0; mi < 4; ++mi)
#pragma unroll
    for (int nj = 0; nj < 4; ++nj)
#pragma unroll
      for (int r = 0; r < 4; ++r)
        C[(long)(bm + r0 + mi * 16 + r) * 1024 + bn + c0t + nj * 16] =
            f2bf(acc[mi][nj][r]);
#undef STG128
}

// ================= 64x64 bf16 GEMM, 4 waves, dbuf LDS, swizzled (R7) =========
// dmode 0: rect; dmode 1: diag (xt,xt); dmode 2: triangle.
// OUTMODE 1: f32 compact per-tile.  OUTMODE 3: bf16 [1024][1024] + mirror (Gram).
template<int OUTMODE>
__global__ __launch_bounds__(256) void gemm64(
    const bf16* __restrict__ A, int lda, long aOffZ,
    const bf16* __restrict__ Bt, int ldb, long btOffZ,
    void* __restrict__ Cv, int ldc, long cOffZ, int loOff,
    int K, int NtN, int dmode, int ksplit)
{
  __shared__ char lds[32768];   // A: [2][8K] ; B at +16384, same

  const int Nx = gridDim.x;
  const int lin = blockIdx.x + Nx * blockIdx.y;
  const int tot = Nx * gridDim.y;
  const int swz = (lin & 7) * (tot >> 3) + (lin >> 3);  // tot%8==0 at all calls
  const int xt = swz % Nx, y = swz / Nx;
  const int zb = y / ksplit, zs = y % ksplit;
  int ti, tj;
  if (dmode == 2)      { tri_decode(xt, &ti, &tj); }
  else if (dmode == 1) { ti = xt; tj = xt; }
  else                 { ti = xt / NtN; tj = xt % NtN; }
  const int bm = ti * 64, bn = tj * 64;

  A  += (long)zb * aOffZ + (long)zs * K;
  Bt += (long)zb * btOffZ + (long)zs * K;

  const int tid  = threadIdx.x;
  const int wid  = tid >> 6;
  const int lane = tid & 63;
  const int wr = (wid >> 1) * 32, wc = (wid & 1) * 32;
  const int frow = lane & 15;
  const int fkb  = (lane >> 4) << 4;
  const unsigned xorv = (unsigned)((lane & 7) << 4);

  // staging source: LDS linear p -> global q = p ^ (((p>>7)&7)<<4)
  const int q0 = (tid * 16) ^ (((tid >> 3) & 7) << 4);
  const int q1 = (4096 + tid * 16) ^ (((tid >> 3) & 7) << 4);
  const int srow0 = q0 >> 7, scol0 = (q0 & 127) >> 1;
  const int srow1 = q1 >> 7, scol1 = (q1 & 127) >> 1;
  const bf16* ag0 = A  + (long)(bm + srow0) * lda + scol0;
  const bf16* ag1 = A  + (long)(bm + srow1) * lda + scol1;
  const bf16* bg0 = Bt + (long)(bn + srow0) * ldb + scol0;
  const bf16* bg1 = Bt + (long)(bn + srow1) * ldb + scol1;

#define STAGE64(buf, kk) do {                                                        \
    __builtin_amdgcn_global_load_lds((as1cvp)(ag0 + (kk)),                           \
        (as3vp)(lds + (buf)*8192 + wid*1024), 16, 0, 0);                             \
    __builtin_amdgcn_global_load_lds((as1cvp)(ag1 + (kk)),                           \
        (as3vp)(lds + (buf)*8192 + 4096 + wid*1024), 16, 0, 0);                      \
    __builtin_amdgcn_global_load_lds((as1cvp)(bg0 + (kk)),                           \
        (as3vp)(lds + 16384 + (buf)*8192 + wid*1024), 16, 0, 0);                     \
    __builtin_amdgcn_global_load_lds((as1cvp)(bg1 + (kk)),                           \
        (as3vp)(lds + 16384 + (buf)*8192 + 4096 + wid*1024), 16, 0, 0);              \
  } while (0)

  const unsigned paB = (unsigned)((wr + frow) * 128 + fkb);
  const unsigned pbB = (unsigned)((wc + frow) * 128 + fkb);

  f32x4 acc[2][2] = {};
  const int NT = K >> 6;

  // prologue: tile 0 fully landed before any read
  STAGE64(0, 0);
  asm volatile("s_waitcnt vmcnt(0)" ::: "memory");
  gpu_barrier();

  for (int t = 0; t < NT; ++t) {
    const int cur = t & 1;
    if (t + 1 < NT) STAGE64(cur ^ 1, (t + 1) * 64);   // issue next (not waited)
    s16x8 a[2][2], b[2][2];
#pragma unroll
    for (int mi = 0; mi < 2; ++mi)
#pragma unroll
      for (int kh = 0; kh < 2; ++kh)
        a[mi][kh] = *(const s16x8*)(lds + cur * 8192 +
                                    ((paB + mi * 2048u + kh * 64u) ^ xorv));
#pragma unroll
    for (int nj = 0; nj < 2; ++nj)
#pragma unroll
      for (int kh = 0; kh < 2; ++kh)
        b[nj][kh] = *(const s16x8*)(lds + 16384 + cur * 8192 +
                                    ((pbB + nj * 2048u + kh * 64u) ^ xorv));
    asm volatile("s_waitcnt lgkmcnt(0)" ::: "memory");
#pragma unroll
    for (int mi = 0; mi < 2; ++mi)
#pragma unroll
      for (int nj = 0; nj < 2; ++nj) {
        acc[mi][nj] = __builtin_amdgcn_mfma_f32_16x16x32_bf16(a[mi][0], b[nj][0], acc[mi][nj], 0, 0, 0);
        acc[mi][nj] = __builtin_amdgcn_mfma_f32_16x16x32_bf16(a[mi][1], b[nj][1], acc[mi][nj], 0, 0, 0);
      }
    // full drain: next-tile loads landed; all waves past reads of buf cur
    asm volatile("s_waitcnt vmcnt(0)" ::: "memory");
    gpu_barrier();
  }

  const int r0 = wr + (lane >> 4) * 4;
  const int c0 = wc + (lane & 15);
  if (OUTMODE == 1) {
    float* C = (float*)Cv + (long)y * cOffZ + (long)xt * 4096;
#pragma unroll
    for (int mi = 0; mi < 2; ++mi)
#pragma unroll
      for (int nj = 0; nj < 2; ++nj)
#pragma unroll
        for (int r = 0; r < 4; ++r)
          C[(r0 + mi * 16 + r) * 64 + c0 + nj * 16] = acc[mi][nj][r];
  } else if (OUTMODE == 3) {
    // Gram: bf16 G[1024][1024] per batch + symmetric mirror
    unsigned short* C = (unsigned short*)Cv + (long)y * cOffZ;
#pragma unroll
    for (int mi = 0; mi < 2; ++mi)
#pragma unroll
      for (int nj = 0; nj < 2; ++nj)
#pragma unroll
        for (int r = 0; r < 4; ++r) {
          const unsigned short h = f2bf(acc[mi][nj][r]);
          const int R = bm + r0 + mi * 16 + r;
          const int Cc = bn + c0 + nj * 16;
          C[(long)R * 1024 + Cc] = h;
          if (ti != tj) C[(long)Cc * 1024 + R] = h;
        }
  } else {
    unsigned short* C = (unsigned short*)Cv + (long)y * cOffZ;
#pragma unroll
    for (int mi = 0; mi < 2; ++mi)
#pragma unroll
      for (int nj = 0; nj < 2; ++nj)
#pragma unroll
        for (int r = 0; r < 4; ++r) {
          const float v = acc[mi][nj][r];
          const unsigned short h = f2bf(v);
          const long idx = (long)(bm + r0 + mi * 16 + r) * ldc + bn + c0 + nj * 16;
          C[idx] = h;
          if (OUTMODE == 2) C[idx + loOff] = f2bf(v - bf2f(h));
        }
  }
#undef STAGE64
}

// ---------- Yt[b][c][h*64+e] = 0.125 * sum_d (sum_s Up) * Wq[h*64+d][c] ------
__global__ __launch_bounds__(256) void yt_kernel(const float* __restrict__ Up,
                                                 const unsigned short* __restrict__ Wqb,
                                                 unsigned short* __restrict__ Yt) {
  __shared__ float Ul[64 * 64];
  __shared__ float Wql[64 * 68];
  const int cblk = blockIdx.x, h = blockIdx.y, z = blockIdx.z;
  const int t = threadIdx.x;

  {
    const int d = t >> 2, e0 = (t & 3) * 16;
#pragma unroll
    for (int q = 0; q < 4; ++q) {
      f32x4 s = {};
#pragma unroll
      for (int sp = 0; sp < 4; ++sp) {
        f32x4 v = *(const f32x4*)&Up[((long)(z * 4 + sp) * 16 + h) * 4096 + d * 64 + e0 + q * 4];
#pragma unroll
        for (int j = 0; j < 4; ++j) s[j] += v[j];
      }
      *(f32x4*)&Ul[d * 64 + e0 + q * 4] = s;
    }
    const unsigned short* wp = Wqb + (long)(h * 64 + d) * 1024 + cblk * 64 + e0;
#pragma unroll
    for (int q = 0; q < 2; ++q) {
      s16x8 w = *(const s16x8*)&wp[q * 8];
#pragma unroll
      for (int j = 0; j < 8; ++j) Wql[d * 68 + e0 + q * 8 + j] = bf2f((unsigned short)w[j]);
    }
  }
  __syncthreads();

  const int jc = t >> 2, e0 = (t & 3) * 16;
  f32x4 acc[4] = {};
  for (int d = 0; d < 64; ++d) {
    const float w = Wql[d * 68 + jc];
    const float* ur = &Ul[d * 64 + e0];
#pragma unroll
    for (int q = 0; q < 4; ++q) {
      f32x4 u4 = *(const f32x4*)&ur[q * 4];
#pragma unroll
      for (int j = 0; j < 4; ++j) acc[q][j] += w * u4[j];
    }
  }
  unsigned short* yp = Yt + (long)z * 1048576 + (long)(cblk * 64 + jc) * 1024 + h * 64 + e0;
#pragma unroll
  for (int q = 0; q < 4; ++q)
#pragma unroll
    for (int j = 0; j < 4; ++j) yp[q * 4 + j] = f2bf(acc[q][j] * 0.125f);
}

extern "C" void kernel_launch(void* const* d_in, const int* in_sizes, int n_in,
                              void* d_out, int out_size, void* d_ws, size_t ws_size,
                              hipStream_t stream) {
  const float* x  = (const float*)d_in[0];
  const float* Wq = (const float*)d_in[1];
  const float* Wk = (const float*)d_in[2];
  const float* Wv = (const float*)d_in[3];
  const float* Wo = (const float*)d_in[4];
  const float* bo = (const float*)d_in[5];
  float* out = (float*)d_out;

  char* ws = (char*)d_ws;
  // layout (bytes): [0,32M) xb | [32M,64M) xT | [64M,76M) weights |
  //   Gb @79691776 (8.4M) | T @88080384 (8.4M) | Up @96468992 (4.2M) |
  //   Yt @113246208 (8.4M) | R @121634816 (8.4M)
  unsigned short* xb  = (unsigned short*)(ws);
  unsigned short* xT  = (unsigned short*)(ws + 33554432);
  unsigned short* Wkb = (unsigned short*)(ws + 67108864);
  unsigned short* Wvb = (unsigned short*)(ws + 71303168);
  unsigned short* Wqb = (unsigned short*)(ws + 75497472);
  unsigned short* Wob = (unsigned short*)(ws + 77594624);
  unsigned short* Gb  = (unsigned short*)(ws + 79691776);
  unsigned short* T   = (unsigned short*)(ws + 88080384);
  float*          Up  = (float*)         (ws + 96468992);
  unsigned short* Yt  = (unsigned short*)(ws + 113246208);
  unsigned short* R   = (unsigned short*)(ws + 121634816);

  // 1) fused casts: x -> xb + xT ; weights -> Wkb/Wvb/Wqb/Wob
  cast_fused<<<dim3(32, 8, 12), 256, 0, stream>>>(
      x, xb, xT, Wq, Wk, Wv, Wo, Wkb, Wvb, Wqb, Wob);

  // 2) G = xT . xT^T direct: 64^2 triangle (136) x 4 batches, K=4096, + mirror
  gemm64<3><<<dim3(136, 4), 256, 0, stream>>>(
      (const bf16*)xT, 4096, 4194304L, (const bf16*)xT, 4096, 4194304L,
      (void*)Gb, 1024, 1048576L, 0, 4096, 1, 2, 1);

  // 3) T = Wk . G  (K=1024), 256 wgs, single bf16 out (R15-proven)
  gemm128<3><<<dim3(64, 4), 256, 0, stream>>>(
      (const bf16*)Wkb, (const bf16*)Gb, (void*)T, nullptr);

  // 4) Up = T . Wv^T diag 64-tiles, K-split 4 (y = b*4+s, K=256), fp32 compact
  gemm64<1><<<dim3(16, 16), 256, 0, stream>>>(
      (const bf16*)T, 1024, 1048576L, (const bf16*)Wvb, 1024, 0L,
      (void*)Up, 64, 65536L, 0, 256, 1, 1, 4);

  // 5) Yt from Up (sums 4 splits) and Wq (applies 0.125 scale)
  yt_kernel<<<dim3(16, 16, 4), 256, 0, stream>>>(Up, Wqb, Yt);

  // 6) R = Wo . Y  (Bt = Yt), 256 wgs, bf16 out (R15-proven)
  gemm128<3><<<dim3(64, 4), 256, 0, stream>>>(
      (const bf16*)Wob, (const bf16*)Yt, (void*)R, nullptr);

  // 7) out = xb . R_b^T + bo  (8-phase gemm256, proven 45.4us)
  gemm256<true><<<dim3(64, 1, 4), 512, 0, stream>>>(
      (const bf16*)xb, 1024, 0L, 4194304L,
      (const bf16*)R, 1024, 0L, 1048576L,
      (void*)out, 1024, 0L, 4194304L,
      bo, 1024, 4, 0);
}